// Round 9
// baseline (347.538 us; speedup 1.0000x reference)
//
#include <hip/hip_runtime.h>
#include <hip/hip_bf16.h>
#include <math.h>

// TopK router: logits = x @ gate_w^T, softmax, top-2, renormalize.
// M=32768 tokens, K=4096, E=64 experts.
// Outputs (concat, harness reads whole buffer as float32):
//   d_out[0 .. 2M)  : top-2 weights (descending)
//   d_out[2M .. 4M) : top-2 expert indices, stored as float values
//
// R9: R5 shape (4 waves = 4-way K-split(1024), 2m x 4n tiles/wave) with a
// rotating-buffer schedule sized to FIT 128 VGPR (4 waves/SIMD) so the
// allocator never serializes loads (R4/R5 suspected failure mode):
//   cvt A(i) -> issue A(i+1) (same regs) -> MFMA bh-group(16) ->
//   issue bh(i+1) (same regs) -> MFMA bl-group(8) -> issue bl(i+1).
// Every load has >=1 MFMA-group+cvt of slack; counted vmcnt keeps younger
// loads in flight. 3-term MFMA (hh+hl+lh), TAU=1e-3 (R3-proven), no NT
// (L3 serves ~half of x across replays). Packed B (prep_b) + parallel
// fp64 refine carried over.

typedef __attribute__((ext_vector_type(8))) short short8;
typedef __attribute__((ext_vector_type(4))) float f32x4;

#define TPB 32      // tokens per block
#define TAU 1e-3f   // near-tie refine threshold (3-term logit noise ~1e-5)
#define LROW 68     // padded logits stride (floats)

__device__ __forceinline__ void cvt8(const f32x4* v, short8* hi, short8* lo) {
    const float* f = reinterpret_cast<const float*>(v);
#pragma unroll
    for (int j = 0; j < 8; ++j) {
        __hip_bfloat16 h = __float2bfloat16(f[j]);
        float r = f[j] - __bfloat162float(h);
        __hip_bfloat16 l = __float2bfloat16(r);
        (*hi)[j] = (short)*reinterpret_cast<unsigned short*>(&h);
        (*lo)[j] = (short)*reinterpret_cast<unsigned short*>(&l);
    }
}

// Pack gw (64x4096 f32) into MFMA-fragment-ordered bf16 hi/lo arrays:
// entry (nt*8192 + w*64 + ln) holds 8 bf16 of row nt*16+(ln&15),
// k = w*32 + (ln>>4)*8 .. +8.  A wave's 64 lanes read 1KB contiguous.
__global__ void prep_b(const float* __restrict__ gw,
                       short8* __restrict__ bh, short8* __restrict__ bl) {
    const int tid = blockIdx.x * 256 + threadIdx.x;   // 0..32767
    const int ln  = tid & 63;
    const int w   = (tid >> 6) & 127;
    const int nt  = tid >> 13;
    const int row = nt * 16 + (ln & 15);
    const int k   = w * 32 + ((ln >> 4) << 3);
    f32x4 v[2];
    v[0] = *reinterpret_cast<const f32x4*>(gw + (long)row * 4096 + k);
    v[1] = *reinterpret_cast<const f32x4*>(gw + (long)row * 4096 + k + 4);
    short8 h, l;
    cvt8(v, &h, &l);
    bh[tid] = h;
    bl[tid] = l;
}

__global__ __launch_bounds__(256, 4)
void router_mfma_topk(const float* __restrict__ x,
                      const short8* __restrict__ bhp,
                      const short8* __restrict__ blp,
                      const float* __restrict__ gw,
                      float* __restrict__ out,
                      int M, int K) {
    __shared__ float Lp[4 * TPB * LROW];    // per-wave partial logits
    __shared__ int flags[TPB];
    __shared__ double Ld4[4][64];

    const int t  = threadIdx.x;
    const int wv = t >> 6;                  // wave -> K-slice of 1024
    const int ln = t & 63;
    const int fr = ln & 15;
    const int q  = ln >> 4;
    const long tok0 = (long)blockIdx.x * TPB;

    const int kbase = wv * 1024 + q * 8;
    const float* pA0 = x + (tok0 + fr) * (long)K + kbase;
    const float* pA1 = x + (tok0 + 16 + fr) * (long)K + kbase;
    const long bidx0 = (long)(wv * 32) * 64 + ln;   // + nt*8192 + w*64

    f32x4 acc[2][4];
#pragma unroll
    for (int mt = 0; mt < 2; ++mt)
#pragma unroll
        for (int nt = 0; nt < 4; ++nt) acc[mt][nt] = (f32x4){0.f, 0.f, 0.f, 0.f};

    // rotating buffers (static indices only)
    f32x4 Af[4];
    short8 bh[4], bl[4];

    // prologue: window 0 loads, in age order A -> bh -> bl
    Af[0] = *reinterpret_cast<const f32x4*>(pA0);
    Af[1] = *reinterpret_cast<const f32x4*>(pA0 + 4);
    Af[2] = *reinterpret_cast<const f32x4*>(pA1);
    Af[3] = *reinterpret_cast<const f32x4*>(pA1 + 4);
#pragma unroll
    for (int nt = 0; nt < 4; ++nt) bh[nt] = bhp[bidx0 + nt * 8192];
#pragma unroll
    for (int nt = 0; nt < 4; ++nt) bl[nt] = blp[bidx0 + nt * 8192];

    for (int i = 0; i < 32; ++i) {
        // ---- step 1: convert A(i) (waits A; bh/bl/younger stay in flight) ----
        short8 ah0, al0, ah1, al1;
        cvt8(&Af[0], &ah0, &al0);
        cvt8(&Af[2], &ah1, &al1);
        __builtin_amdgcn_sched_barrier(0);
        // ---- step 2: issue A(i+1) into the same regs ----
        {
            const int p = (i + 1 < 32) ? (i + 1) * 32 : 0;
            Af[0] = *reinterpret_cast<const f32x4*>(pA0 + p);
            Af[1] = *reinterpret_cast<const f32x4*>(pA0 + p + 4);
            Af[2] = *reinterpret_cast<const f32x4*>(pA1 + p);
            Af[3] = *reinterpret_cast<const f32x4*>(pA1 + p + 4);
        }
        __builtin_amdgcn_sched_barrier(0);
        // ---- step 3: bh-group, 16 MFMA (waits bh(i); younger fly) ----
#pragma unroll
        for (int nt = 0; nt < 4; ++nt) {
            acc[0][nt] = __builtin_amdgcn_mfma_f32_16x16x32_bf16(ah0, bh[nt], acc[0][nt], 0, 0, 0);
            acc[0][nt] = __builtin_amdgcn_mfma_f32_16x16x32_bf16(al0, bh[nt], acc[0][nt], 0, 0, 0);
            acc[1][nt] = __builtin_amdgcn_mfma_f32_16x16x32_bf16(ah1, bh[nt], acc[1][nt], 0, 0, 0);
            acc[1][nt] = __builtin_amdgcn_mfma_f32_16x16x32_bf16(al1, bh[nt], acc[1][nt], 0, 0, 0);
        }
        __builtin_amdgcn_sched_barrier(0);
        // ---- step 4: issue bh(i+1) into the same regs ----
        {
            const long nb = bidx0 + (long)((i + 1 < 32) ? i + 1 : 31) * 64;
#pragma unroll
            for (int nt = 0; nt < 4; ++nt) bh[nt] = bhp[nb + nt * 8192];
        }
        __builtin_amdgcn_sched_barrier(0);
        // ---- step 5: bl-group, 8 MFMA (waits bl(i); younger fly) ----
#pragma unroll
        for (int nt = 0; nt < 4; ++nt) {
            acc[0][nt] = __builtin_amdgcn_mfma_f32_16x16x32_bf16(ah0, bl[nt], acc[0][nt], 0, 0, 0);
            acc[1][nt] = __builtin_amdgcn_mfma_f32_16x16x32_bf16(ah1, bl[nt], acc[1][nt], 0, 0, 0);
        }
        __builtin_amdgcn_sched_barrier(0);
        // ---- step 6: issue bl(i+1) into the same regs ----
        {
            const long nb = bidx0 + (long)((i + 1 < 32) ? i + 1 : 31) * 64;
#pragma unroll
            for (int nt = 0; nt < 4; ++nt) bl[nt] = blp[nb + nt * 8192];
        }
        __builtin_amdgcn_sched_barrier(0);
    }

    // ---- dump per-wave partials: C/D layout col=lane&15, row=q*4+r ----
    float* myLp = Lp + wv * (TPB * LROW);
#pragma unroll
    for (int mt = 0; mt < 2; ++mt)
#pragma unroll
        for (int nt = 0; nt < 4; ++nt)
#pragma unroll
            for (int r = 0; r < 4; ++r) {
                const int tokl = mt * 16 + q * 4 + r;
                const int e    = nt * 16 + fr;
                myLp[tokl * LROW + e] = acc[mt][nt][r];
            }
    __syncthreads();

    // ---- cross-wave reduce into Lp[0] region ----
    for (int i = t; i < TPB * LROW; i += 256)
        Lp[i] = (Lp[i] + Lp[TPB * LROW + i])
              + (Lp[2 * TPB * LROW + i] + Lp[3 * TPB * LROW + i]);
    __syncthreads();

    // ---- top-3 scan + provisional output + near-tie flag ----
    if (t < TPB) {
        const float* row = Lp + (long)t * LROW;
        float m1 = -INFINITY, m2 = -INFINITY, m3 = -INFINITY;
        int i1 = 0, i2 = 0;
#pragma unroll 8
        for (int e = 0; e < 64; ++e) {
            const float v = row[e];
            if (v > m1)      { m3 = m2; m2 = m1; i2 = i1; m1 = v; i1 = e; }
            else if (v > m2) { m3 = m2; m2 = v; i2 = e; }
            else if (v > m3) { m3 = v; }
        }
        const float e2 = expf(m2 - m1);
        const float s  = 1.0f + e2;

        const long g = tok0 + t;
        out[2 * g + 0] = 1.0f / s;
        out[2 * g + 1] = e2 / s;
        float* oi = out + 2 * (long)M;
        oi[2 * g + 0] = (float)i1;
        oi[2 * g + 1] = (float)i2;

        flags[t] = ((m1 - m2) < TAU) | ((m2 - m3) < TAU);
    }
    __syncthreads();

    // ---- fp64 refine, 256 threads cooperate (wave=K-quarter, lane=expert) ----
    for (int tk = 0; tk < TPB; ++tk) {
        if (flags[tk]) {
            const float* xr = x + (tok0 + tk) * (long)K + wv * 1024;
            const float* gr = gw + (long)ln * (long)K + wv * 1024;
            double s0 = 0.0, s1 = 0.0, s2 = 0.0, s3 = 0.0;
            for (int k = 0; k < 1024; k += 4) {
                const f32x4 a = *reinterpret_cast<const f32x4*>(xr + k);
                const f32x4 b = *reinterpret_cast<const f32x4*>(gr + k);
                s0 = fma((double)a.x, (double)b.x, s0);
                s1 = fma((double)a.y, (double)b.y, s1);
                s2 = fma((double)a.z, (double)b.z, s2);
                s3 = fma((double)a.w, (double)b.w, s3);
            }
            Ld4[wv][ln] = (s0 + s1) + (s2 + s3);
            __syncthreads();
            if (t == 0) {
                double m1 = -INFINITY, m2 = -INFINITY;
                int i1 = 0, i2 = 0;
                for (int e = 0; e < 64; ++e) {
                    const double v = Ld4[0][e] + Ld4[1][e] + Ld4[2][e] + Ld4[3][e];
                    if (v > m1)      { m2 = m1; i2 = i1; m1 = v; i1 = e; }
                    else if (v > m2) { m2 = v; i2 = e; }
                }
                const double e2 = exp(m2 - m1);
                const double s  = 1.0 + e2;
                const long g = tok0 + tk;
                out[2 * g + 0] = (float)(1.0 / s);
                out[2 * g + 1] = (float)(e2 / s);
                float* oi = out + 2 * (long)M;
                oi[2 * g + 0] = (float)i1;
                oi[2 * g + 1] = (float)i2;
            }
            __syncthreads();
        }
    }
}

extern "C" void kernel_launch(void* const* d_in, const int* in_sizes, int n_in,
                              void* d_out, int out_size, void* d_ws, size_t ws_size,
                              hipStream_t stream) {
    const float* x  = (const float*)d_in[0];
    const float* gw = (const float*)d_in[1];
    float* out = (float*)d_out;

    const int K = 4096;
    const int M = in_sizes[0] / K;          // 32768 tokens
    const int nblocks = M / TPB;            // 1024

    short8* bh = (short8*)d_ws;
    short8* bl = bh + 32768;
    prep_b<<<128, 256, 0, stream>>>(gw, bh, bl);
    router_mfma_topk<<<nblocks, 256, 0, stream>>>(x, bh, bl, gw, out, M, K);
}

// Round 11
// 290.297 us; speedup vs baseline: 1.1972x; 1.1972x over previous
//
#include <hip/hip_runtime.h>
#include <hip/hip_bf16.h>
#include <math.h>

// TopK router: logits = x @ gate_w^T, softmax, top-2, renormalize.
// M=32768 tokens, K=4096, E=64 experts.
// Outputs (concat, harness reads whole buffer as float32):
//   d_out[0 .. 2M)  : top-2 weights (descending)
//   d_out[2M .. 4M) : top-2 expert indices, stored as float values
//
// R11 = R10 with the gemm_part RACE FIXED: the 4 waves' partial tiles are
// reduced in LDS (Wp[4][2048], router_single's proven pattern) and ONE
// reduced tile per block is written to global scratch. Structure:
//   prep_b      : pack gw -> bf16 hi/lo MFMA fragments (1 MB, L2-hot)
//   gemm_part   : streaming partial GEMM, nkc x 1024 blocks
//   reduce_topk : sum nkc partials + top-3/TAU/fp64-refine epilogue
// Fallback: R8-equivalent single kernel if ws too small.

typedef __attribute__((ext_vector_type(8))) short short8;
typedef __attribute__((ext_vector_type(4))) float f32x4;

#define TAU 1e-4f   // near-tie refine threshold (4-term logit noise ~1e-6)
#define LROW 68     // padded logits stride (floats)

__device__ __forceinline__ void cvt8(const f32x4* v, short8* hi, short8* lo) {
    const float* f = reinterpret_cast<const float*>(v);
#pragma unroll
    for (int j = 0; j < 8; ++j) {
        __hip_bfloat16 h = __float2bfloat16(f[j]);
        float r = f[j] - __bfloat162float(h);
        __hip_bfloat16 l = __float2bfloat16(r);
        (*hi)[j] = (short)*reinterpret_cast<unsigned short*>(&h);
        (*lo)[j] = (short)*reinterpret_cast<unsigned short*>(&l);
    }
}

// Pack gw (64x4096 f32) into MFMA-fragment-ordered bf16 hi/lo arrays:
// entry (nt*8192 + w*64 + ln) holds 8 bf16 of row nt*16+(ln&15),
// k = w*32 + (ln>>4)*8 .. +8.  A wave's 64 lanes read 1KB contiguous.
__global__ void prep_b(const float* __restrict__ gw,
                       short8* __restrict__ bh, short8* __restrict__ bl) {
    const int tid = blockIdx.x * 256 + threadIdx.x;   // 0..32767
    const int ln  = tid & 63;
    const int w   = (tid >> 6) & 127;
    const int nt  = tid >> 13;
    const int row = nt * 16 + (ln & 15);
    const int k   = w * 32 + ((ln >> 4) << 3);
    f32x4 v[2];
    v[0] = *reinterpret_cast<const f32x4*>(gw + (long)row * 4096 + k);
    v[1] = *reinterpret_cast<const f32x4*>(gw + (long)row * 4096 + k + 4);
    short8 h, l;
    cvt8(v, &h, &l);
    bh[tid] = h;
    bl[tid] = l;
}

// One k=32 window (R5/R8-proven): B loads, cvt current A, prefetch next A
// into the same regs, then 32 MFMA (4-term hh+hl+lh+ll).
#define WSTEP(WIDX, PREOFF) do {                                              \
    const long bi = bidx0 + (long)(WIDX) * 64;                                \
    short8 bh0 = bhp[bi], bh1 = bhp[bi + 8192],                               \
           bh2 = bhp[bi + 16384], bh3 = bhp[bi + 24576];                      \
    short8 bl0 = blp[bi], bl1 = blp[bi + 8192],                               \
           bl2 = blp[bi + 16384], bl3 = blp[bi + 24576];                      \
    short8 ah0, al0, ah1, al1;                                                \
    cvt8(&A0[0][0], &ah0, &al0);                                              \
    cvt8(&A0[1][0], &ah1, &al1);                                              \
    A0[0][0] = *reinterpret_cast<const f32x4*>(pA0 + (PREOFF));               \
    A0[0][1] = *reinterpret_cast<const f32x4*>(pA0 + (PREOFF) + 4);           \
    A0[1][0] = *reinterpret_cast<const f32x4*>(pA1 + (PREOFF));               \
    A0[1][1] = *reinterpret_cast<const f32x4*>(pA1 + (PREOFF) + 4);           \
    __builtin_amdgcn_sched_barrier(0);                                        \
    acc[0][0] = __builtin_amdgcn_mfma_f32_16x16x32_bf16(ah0, bh0, acc[0][0], 0, 0, 0); \
    acc[0][0] = __builtin_amdgcn_mfma_f32_16x16x32_bf16(ah0, bl0, acc[0][0], 0, 0, 0); \
    acc[0][0] = __builtin_amdgcn_mfma_f32_16x16x32_bf16(al0, bh0, acc[0][0], 0, 0, 0); \
    acc[0][0] = __builtin_amdgcn_mfma_f32_16x16x32_bf16(al0, bl0, acc[0][0], 0, 0, 0); \
    acc[0][1] = __builtin_amdgcn_mfma_f32_16x16x32_bf16(ah0, bh1, acc[0][1], 0, 0, 0); \
    acc[0][1] = __builtin_amdgcn_mfma_f32_16x16x32_bf16(ah0, bl1, acc[0][1], 0, 0, 0); \
    acc[0][1] = __builtin_amdgcn_mfma_f32_16x16x32_bf16(al0, bh1, acc[0][1], 0, 0, 0); \
    acc[0][1] = __builtin_amdgcn_mfma_f32_16x16x32_bf16(al0, bl1, acc[0][1], 0, 0, 0); \
    acc[0][2] = __builtin_amdgcn_mfma_f32_16x16x32_bf16(ah0, bh2, acc[0][2], 0, 0, 0); \
    acc[0][2] = __builtin_amdgcn_mfma_f32_16x16x32_bf16(ah0, bl2, acc[0][2], 0, 0, 0); \
    acc[0][2] = __builtin_amdgcn_mfma_f32_16x16x32_bf16(al0, bh2, acc[0][2], 0, 0, 0); \
    acc[0][2] = __builtin_amdgcn_mfma_f32_16x16x32_bf16(al0, bl2, acc[0][2], 0, 0, 0); \
    acc[0][3] = __builtin_amdgcn_mfma_f32_16x16x32_bf16(ah0, bh3, acc[0][3], 0, 0, 0); \
    acc[0][3] = __builtin_amdgcn_mfma_f32_16x16x32_bf16(ah0, bl3, acc[0][3], 0, 0, 0); \
    acc[0][3] = __builtin_amdgcn_mfma_f32_16x16x32_bf16(al0, bh3, acc[0][3], 0, 0, 0); \
    acc[0][3] = __builtin_amdgcn_mfma_f32_16x16x32_bf16(al0, bl3, acc[0][3], 0, 0, 0); \
    acc[1][0] = __builtin_amdgcn_mfma_f32_16x16x32_bf16(ah1, bh0, acc[1][0], 0, 0, 0); \
    acc[1][0] = __builtin_amdgcn_mfma_f32_16x16x32_bf16(ah1, bl0, acc[1][0], 0, 0, 0); \
    acc[1][0] = __builtin_amdgcn_mfma_f32_16x16x32_bf16(al1, bh0, acc[1][0], 0, 0, 0); \
    acc[1][0] = __builtin_amdgcn_mfma_f32_16x16x32_bf16(al1, bl0, acc[1][0], 0, 0, 0); \
    acc[1][1] = __builtin_amdgcn_mfma_f32_16x16x32_bf16(ah1, bh1, acc[1][1], 0, 0, 0); \
    acc[1][1] = __builtin_amdgcn_mfma_f32_16x16x32_bf16(ah1, bl1, acc[1][1], 0, 0, 0); \
    acc[1][1] = __builtin_amdgcn_mfma_f32_16x16x32_bf16(al1, bh1, acc[1][1], 0, 0, 0); \
    acc[1][1] = __builtin_amdgcn_mfma_f32_16x16x32_bf16(al1, bl1, acc[1][1], 0, 0, 0); \
    acc[1][2] = __builtin_amdgcn_mfma_f32_16x16x32_bf16(ah1, bh2, acc[1][2], 0, 0, 0); \
    acc[1][2] = __builtin_amdgcn_mfma_f32_16x16x32_bf16(ah1, bl2, acc[1][2], 0, 0, 0); \
    acc[1][2] = __builtin_amdgcn_mfma_f32_16x16x32_bf16(al1, bh2, acc[1][2], 0, 0, 0); \
    acc[1][2] = __builtin_amdgcn_mfma_f32_16x16x32_bf16(al1, bl2, acc[1][2], 0, 0, 0); \
    acc[1][3] = __builtin_amdgcn_mfma_f32_16x16x32_bf16(ah1, bh3, acc[1][3], 0, 0, 0); \
    acc[1][3] = __builtin_amdgcn_mfma_f32_16x16x32_bf16(ah1, bl3, acc[1][3], 0, 0, 0); \
    acc[1][3] = __builtin_amdgcn_mfma_f32_16x16x32_bf16(al1, bh3, acc[1][3], 0, 0, 0); \
    acc[1][3] = __builtin_amdgcn_mfma_f32_16x16x32_bf16(al1, bl3, acc[1][3], 0, 0, 0); \
} while (0)

// Phase 2: streaming partial GEMM. Block = (kc, tt): 32 tokens x 64 experts
// over K-chunk kc; 4 waves K-split the chunk; LDS-reduce the 4 wave
// partials (race-free) and write ONE tile per block to global scratch.
__global__ __launch_bounds__(256, 4)
void gemm_part(const float* __restrict__ x,
               const short8* __restrict__ bhp,
               const short8* __restrict__ blp,
               float* __restrict__ part,
               int M, int K, int nkc, int ttiles) {
    __shared__ float Wp[4][2048];

    const int t  = threadIdx.x;
    const int wv = t >> 6;
    const int ln = t & 63;
    const int fr = ln & 15;
    const int q  = ln >> 4;
    const int tt = blockIdx.x % ttiles;
    const int kc = blockIdx.x / ttiles;
    const long tok0 = (long)tt * 32;

    const int kper    = K / nkc;        // K covered by this block
    const int kwave   = kper >> 2;      // per wave
    const int windows = kwave >> 5;     // k=32 windows per wave
    const int kbase   = kc * kper + wv * kwave + q * 8;
    const int wstart  = (kc * kper + wv * kwave) >> 5;

    const float* pA0 = x + (tok0 + fr) * (long)K + kbase;
    const float* pA1 = x + (tok0 + 16 + fr) * (long)K + kbase;
    const long bidx0 = (long)wstart * 64 + ln;   // + nt*8192 + w*64

    f32x4 acc[2][4];
#pragma unroll
    for (int mt = 0; mt < 2; ++mt)
#pragma unroll
        for (int nt = 0; nt < 4; ++nt) acc[mt][nt] = (f32x4){0.f, 0.f, 0.f, 0.f};

    f32x4 A0[2][2];
    A0[0][0] = *reinterpret_cast<const f32x4*>(pA0);
    A0[0][1] = *reinterpret_cast<const f32x4*>(pA0 + 4);
    A0[1][0] = *reinterpret_cast<const f32x4*>(pA1);
    A0[1][1] = *reinterpret_cast<const f32x4*>(pA1 + 4);

    for (int i = 0; i < windows; ++i) {
        const int pre = (i + 1 < windows) ? (i + 1) * 32 : 0;
        WSTEP(i, pre);
    }

    // per-wave partial -> LDS (C/D layout col=lane&15, row=q*4+r)
    float* myW = &Wp[wv][0];
#pragma unroll
    for (int mt = 0; mt < 2; ++mt)
#pragma unroll
        for (int nt = 0; nt < 4; ++nt)
#pragma unroll
            for (int r = 0; r < 4; ++r)
                myW[(mt * 16 + q * 4 + r) * 64 + nt * 16 + fr] = acc[mt][nt][r];
    __syncthreads();

    // block-reduce 4 wave partials, single coalesced global write
    float* pt = part + ((long)kc * ttiles + tt) * 2048;
    for (int idx = t; idx < 2048; idx += 256)
        pt[idx] = (Wp[0][idx] + Wp[1][idx]) + (Wp[2][idx] + Wp[3][idx]);
}

// Phase 3: reduce partials, top-2 + softmax-of-top-2, fp64 refine near-ties.
__global__ __launch_bounds__(256, 2)
void reduce_topk(const float* __restrict__ part,
                 const float* __restrict__ x,
                 const float* __restrict__ gw,
                 float* __restrict__ out,
                 int M, int K, int nkc, int ttiles) {
    __shared__ float Ls[64 * LROW];
    __shared__ int flags[64];
    __shared__ double Ld4[4][64];

    const int t  = threadIdx.x;
    const int wv = t >> 6;
    const int ln = t & 63;
    const long g0 = (long)blockIdx.x * 64;

    for (int idx = t; idx < 4096; idx += 256) {
        const int tok = idx >> 6, e = idx & 63;
        const int tt  = (int)(g0 >> 5) + (tok >> 5);
        const int rr  = tok & 31;
        float s = 0.f;
        for (int kc = 0; kc < nkc; ++kc)
            s += part[((long)kc * ttiles + tt) * 2048 + rr * 64 + e];
        Ls[tok * LROW + e] = s;
    }
    __syncthreads();

    if (t < 64) {
        const float* row = Ls + (long)t * LROW;
        float m1 = -INFINITY, m2 = -INFINITY, m3 = -INFINITY;
        int i1 = 0, i2 = 0;
#pragma unroll 8
        for (int e = 0; e < 64; ++e) {
            const float v = row[e];
            if (v > m1)      { m3 = m2; m2 = m1; i2 = i1; m1 = v; i1 = e; }
            else if (v > m2) { m3 = m2; m2 = v; i2 = e; }
            else if (v > m3) { m3 = v; }
        }
        const float e2 = expf(m2 - m1);
        const float s  = 1.0f + e2;

        const long g = g0 + t;
        out[2 * g + 0] = 1.0f / s;
        out[2 * g + 1] = e2 / s;
        float* oi = out + 2 * (long)M;
        oi[2 * g + 0] = (float)i1;
        oi[2 * g + 1] = (float)i2;

        flags[t] = ((m1 - m2) < TAU) | ((m2 - m3) < TAU);
    }
    __syncthreads();

    for (int tk = 0; tk < 64; ++tk) {
        if (flags[tk]) {
            const float* xr = x + (g0 + tk) * (long)K + wv * 1024;
            const float* gr = gw + (long)ln * (long)K + wv * 1024;
            double s0 = 0.0, s1 = 0.0, s2 = 0.0, s3 = 0.0;
            for (int k = 0; k < 1024; k += 4) {
                const f32x4 a = *reinterpret_cast<const f32x4*>(xr + k);
                const f32x4 b = *reinterpret_cast<const f32x4*>(gr + k);
                s0 = fma((double)a.x, (double)b.x, s0);
                s1 = fma((double)a.y, (double)b.y, s1);
                s2 = fma((double)a.z, (double)b.z, s2);
                s3 = fma((double)a.w, (double)b.w, s3);
            }
            Ld4[wv][ln] = (s0 + s1) + (s2 + s3);
            __syncthreads();
            if (t == 0) {
                double m1 = -INFINITY, m2 = -INFINITY;
                int i1 = 0, i2 = 0;
                for (int e = 0; e < 64; ++e) {
                    const double v = Ld4[0][e] + Ld4[1][e] + Ld4[2][e] + Ld4[3][e];
                    if (v > m1)      { m2 = m1; i2 = i1; m1 = v; i1 = e; }
                    else if (v > m2) { m2 = v; i2 = e; }
                }
                const double e2 = exp(m2 - m1);
                const double s  = 1.0 + e2;
                const long g = g0 + tk;
                out[2 * g + 0] = (float)(1.0 / s);
                out[2 * g + 1] = (float)(e2 / s);
                float* oi = out + 2 * (long)M;
                oi[2 * g + 0] = (float)i1;
                oi[2 * g + 1] = (float)i2;
            }
            __syncthreads();
        }
    }
}

// Fallback (ws too small for partials): R8-equivalent single kernel.
__global__ __launch_bounds__(256, 4)
void router_single(const float* __restrict__ x,
                   const short8* __restrict__ bhp,
                   const short8* __restrict__ blp,
                   const float* __restrict__ gw,
                   float* __restrict__ out,
                   int M, int K) {
    __shared__ float Lp[4 * 32 * LROW];
    __shared__ int flags[32];
    __shared__ double Ld4[4][64];

    const int t  = threadIdx.x;
    const int wv = t >> 6;
    const int ln = t & 63;
    const int fr = ln & 15;
    const int q  = ln >> 4;
    const long tok0 = (long)blockIdx.x * 32;

    const int kbase = wv * 1024 + q * 8;
    const float* pA0 = x + (tok0 + fr) * (long)K + kbase;
    const float* pA1 = x + (tok0 + 16 + fr) * (long)K + kbase;
    const long bidx0 = (long)(wv * 32) * 64 + ln;

    f32x4 acc[2][4];
#pragma unroll
    for (int mt = 0; mt < 2; ++mt)
#pragma unroll
        for (int nt = 0; nt < 4; ++nt) acc[mt][nt] = (f32x4){0.f, 0.f, 0.f, 0.f};

    f32x4 A0[2][2];
    A0[0][0] = *reinterpret_cast<const f32x4*>(pA0);
    A0[0][1] = *reinterpret_cast<const f32x4*>(pA0 + 4);
    A0[1][0] = *reinterpret_cast<const f32x4*>(pA1);
    A0[1][1] = *reinterpret_cast<const f32x4*>(pA1 + 4);

    for (int i = 0; i < 32; ++i) {
        const int pre = (i + 1 < 32) ? (i + 1) * 32 : 0;
        WSTEP(i, pre);
    }

    float* myLp = Lp + wv * (32 * LROW);
#pragma unroll
    for (int mt = 0; mt < 2; ++mt)
#pragma unroll
        for (int nt = 0; nt < 4; ++nt)
#pragma unroll
            for (int r = 0; r < 4; ++r)
                myLp[(mt * 16 + q * 4 + r) * LROW + nt * 16 + fr] = acc[mt][nt][r];
    __syncthreads();

    for (int i = t; i < 32 * LROW; i += 256)
        Lp[i] = (Lp[i] + Lp[32 * LROW + i])
              + (Lp[2 * 32 * LROW + i] + Lp[3 * 32 * LROW + i]);
    __syncthreads();

    if (t < 32) {
        const float* row = Lp + (long)t * LROW;
        float m1 = -INFINITY, m2 = -INFINITY, m3 = -INFINITY;
        int i1 = 0, i2 = 0;
#pragma unroll 8
        for (int e = 0; e < 64; ++e) {
            const float v = row[e];
            if (v > m1)      { m3 = m2; m2 = m1; i2 = i1; m1 = v; i1 = e; }
            else if (v > m2) { m3 = m2; m2 = v; i2 = e; }
            else if (v > m3) { m3 = v; }
        }
        const float e2 = expf(m2 - m1);
        const float s  = 1.0f + e2;
        const long g = tok0 + t;
        out[2 * g + 0] = 1.0f / s;
        out[2 * g + 1] = e2 / s;
        float* oi = out + 2 * (long)M;
        oi[2 * g + 0] = (float)i1;
        oi[2 * g + 1] = (float)i2;
        flags[t] = ((m1 - m2) < TAU) | ((m2 - m3) < TAU);
    }
    __syncthreads();

    for (int tk = 0; tk < 32; ++tk) {
        if (flags[tk]) {
            const float* xr = x + (tok0 + tk) * (long)K + wv * 1024;
            const float* gr = gw + (long)ln * (long)K + wv * 1024;
            double s0 = 0.0, s1 = 0.0, s2 = 0.0, s3 = 0.0;
            for (int k = 0; k < 1024; k += 4) {
                const f32x4 a = *reinterpret_cast<const f32x4*>(xr + k);
                const f32x4 b = *reinterpret_cast<const f32x4*>(gr + k);
                s0 = fma((double)a.x, (double)b.x, s0);
                s1 = fma((double)a.y, (double)b.y, s1);
                s2 = fma((double)a.z, (double)b.z, s2);
                s3 = fma((double)a.w, (double)b.w, s3);
            }
            Ld4[wv][ln] = (s0 + s1) + (s2 + s3);
            __syncthreads();
            if (t == 0) {
                double m1 = -INFINITY, m2 = -INFINITY;
                int i1 = 0, i2 = 0;
                for (int e = 0; e < 64; ++e) {
                    const double v = Ld4[0][e] + Ld4[1][e] + Ld4[2][e] + Ld4[3][e];
                    if (v > m1)      { m2 = m1; i2 = i1; m1 = v; i1 = e; }
                    else if (v > m2) { m2 = v; i2 = e; }
                }
                const double e2 = exp(m2 - m1);
                const double s  = 1.0 + e2;
                const long g = tok0 + tk;
                out[2 * g + 0] = (float)(1.0 / s);
                out[2 * g + 1] = (float)(e2 / s);
                float* oi = out + 2 * (long)M;
                oi[2 * g + 0] = (float)i1;
                oi[2 * g + 1] = (float)i2;
            }
            __syncthreads();
        }
    }
}

extern "C" void kernel_launch(void* const* d_in, const int* in_sizes, int n_in,
                              void* d_out, int out_size, void* d_ws, size_t ws_size,
                              hipStream_t stream) {
    const float* x  = (const float*)d_in[0];
    const float* gw = (const float*)d_in[1];
    float* out = (float*)d_out;

    const int K = 4096;
    const int M = in_sizes[0] / K;          // 32768 tokens
    const int ttiles = M / 32;              // 1024

    const size_t bbytes = 2ull * 32768 * sizeof(short8);   // 1 MB packed B
    const size_t per_kc = (size_t)M * 64 * sizeof(float);  // 8 MB partials

    short8* bh = (short8*)d_ws;
    short8* bl = bh + 32768;
    float* part = (float*)(bl + 32768);

    int nkc = 0;
    if (ws_size >= bbytes + 4 * per_kc)      nkc = 4;
    else if (ws_size >= bbytes + 2 * per_kc) nkc = 2;
    else if (ws_size >= bbytes + 1 * per_kc) nkc = 1;

    prep_b<<<128, 256, 0, stream>>>(gw, bh, bl);
    if (nkc > 0) {
        gemm_part<<<nkc * ttiles, 256, 0, stream>>>(x, bh, bl, part, M, K, nkc, ttiles);
        reduce_topk<<<M / 64, 256, 0, stream>>>(part, x, gw, out, M, K, nkc, ttiles);
    } else {
        router_single<<<ttiles, 256, 0, stream>>>(x, bh, bl, gw, out, M, K);
    }
}